// Round 1
// baseline (441.310 us; speedup 1.0000x reference)
//
#include <hip/hip_runtime.h>
#include <math.h>

#define KTOT 69
#define NRADC 24
#define NFEAT 216
#define NELEMC 94
#define EMBC 16
#define H1C 256
#define H2C 128
#define CE 8

// ---- static lxlylz tables (z=1..4 concatenated; offsets 0,4,14,34) ----
__device__ __constant__ int c_lx[KTOT] = {
  0,0,0,1,
  0,0,0,1,0,0,0,1,1,2,
  0,0,0,1,0,0,0,1,1,2,0,0,0,0,1,1,1,2,2,3,
  0,0,0,1,0,0,0,1,1,2,0,0,0,0,1,1,1,2,2,3,0,0,0,0,0,1,1,1,1,2,2,2,3,3,4};
__device__ __constant__ int c_ly[KTOT] = {
  0,0,1,0,
  0,0,1,0,0,1,2,0,1,0,
  0,0,1,0,0,1,2,0,1,0,0,1,2,3,0,1,2,0,1,0,
  0,0,1,0,0,1,2,0,1,0,0,1,2,3,0,1,2,0,1,0,0,1,2,3,4,0,1,2,3,0,1,2,0,1,0};
__device__ __constant__ int c_lz[KTOT] = {
  0,1,0,0,
  0,1,0,0,2,1,0,1,0,0,
  0,1,0,0,2,1,0,1,0,0,3,2,1,0,2,1,0,1,0,0,
  0,1,0,0,2,1,0,1,0,0,3,2,1,0,2,1,0,1,0,0,4,3,2,1,0,3,2,1,0,2,1,0,1,0,0};
__device__ __constant__ float c_fn[KTOT] = {
  1,1,1,1,
  1,2,2,2,1,2,1,2,2,1,
  1,3,3,3,3,6,3,6,6,3,1,3,3,1,3,6,3,3,3,1,
  1,4,4,4,6,12,6,12,12,6,4,12,12,4,12,24,12,12,12,4,
  1,4,6,4,1,4,12,12,4,6,12,6,4,4,1};
__device__ __constant__ float c_lam[KTOT] = {
  1,-1,-1,-1,
  1,-1,-1,-1,1,1,1,1,1,1,
  1,-1,-1,-1,1,1,1,1,1,1,-1,-1,-1,-1,-1,-1,-1,-1,-1,-1,
  1,-1,-1,-1,1,1,1,1,1,1,-1,-1,-1,-1,-1,-1,-1,-1,-1,-1,
  1,1,1,1,1,1,1,1,1,1,1,1,1,1,1};
__device__ __constant__ int c_zid[KTOT] = {
  0,0,0,0,
  1,1,1,1,1,1,1,1,1,1,
  2,2,2,2,2,2,2,2,2,2,2,2,2,2,2,2,2,2,2,2,
  3,3,3,3,3,3,3,3,3,3,3,3,3,3,3,3,3,3,3,3,3,3,3,3,3,3,3,3,3,3,3,3,3,3,3};
__device__ __constant__ int c_k0[4] = {0,4,14,34};
__device__ __constant__ int c_kn[4] = {4,10,20,35};
__device__ __constant__ float c_zn[4] = {1.0f, 0.5f, 0.25f, 0.125f};

__device__ __forceinline__ float silu(float x) { return x / (1.0f + expf(-x)); }
__device__ __forceinline__ float4 silu4(float4 v) {
  v.x = silu(v.x); v.y = silu(v.y); v.z = silu(v.z); v.w = silu(v.w); return v;
}
__device__ __forceinline__ void fma4(float4& a, float s, const float4 w) {
  a.x += s * w.x; a.y += s * w.y; a.z += s * w.z; a.w += s * w.w;
}

// ---------------- Kernel 1: per-edge radial MLP ----------------
// radial output stored TRANSPOSED as float4: radial4[o4 * E + e], o4 in [0,30)
__global__ __launch_bounds__(128) void k_edge(
    const float* __restrict__ rij,
    const float* __restrict__ Wr1, const float* __restrict__ br1,
    const float* __restrict__ Wr2, const float* __restrict__ br2,
    float4* __restrict__ radial4, int E) {
  __shared__ __align__(16) float s_w1[NRADC * 64];
  __shared__ __align__(16) float s_w2[64 * 120];
  __shared__ __align__(16) float s_b1[64];
  __shared__ __align__(16) float s_b2[120];
  const int tid = threadIdx.x;
  for (int i = tid; i < NRADC * 64; i += 128) s_w1[i] = Wr1[i];
  for (int i = tid; i < 64 * 120; i += 128) s_w2[i] = Wr2[i];
  if (tid < 64) s_b1[tid] = br1[tid];
  for (int i = tid; i < 120; i += 128) s_b2[i] = br2[i];
  __syncthreads();

  const int base = blockIdx.x * 256;
  const int e0v = base + tid;
  const int e1v = base + 128 + tid;

  float bas[2][NRADC];
  const int ee[2] = {e0v, e1v};
  #pragma unroll
  for (int c = 0; c < 2; ++c) {
    if (ee[c] < E) {
      float x = rij[ee[c] * 3 + 0], y = rij[ee[c] * 3 + 1], z = rij[ee[c] * 3 + 2];
      float r = sqrtf(x * x + y * y + z * z);
      float rc = fminf(r, 6.0f);
      float fcv = 0.5f * (cosf(3.14159265358979323846f * rc * (1.0f / 6.0f)) + 1.0f);
      #pragma unroll
      for (int m = 0; m < NRADC; ++m) {
        float d = r - (6.0f / 23.0f) * (float)m;
        bas[c][m] = expf(-8.0f * d * d) * fcv;
      }
    } else {
      #pragma unroll
      for (int m = 0; m < NRADC; ++m) bas[c][m] = 0.0f;
    }
  }

  // layer 1: basis[24] -> h[64], both edges share weight reads
  float h0[64], h1[64];
  const float4* w1v = (const float4*)s_w1;   // [24][16]
  const float4* b1v = (const float4*)s_b1;   // [16]
  #pragma unroll
  for (int j4 = 0; j4 < 16; ++j4) {
    float4 a0 = b1v[j4], a1 = b1v[j4];
    #pragma unroll
    for (int m = 0; m < NRADC; ++m) {
      float4 w = w1v[m * 16 + j4];
      fma4(a0, bas[0][m], w);
      fma4(a1, bas[1][m], w);
    }
    h0[4 * j4 + 0] = silu(a0.x); h0[4 * j4 + 1] = silu(a0.y);
    h0[4 * j4 + 2] = silu(a0.z); h0[4 * j4 + 3] = silu(a0.w);
    h1[4 * j4 + 0] = silu(a1.x); h1[4 * j4 + 1] = silu(a1.y);
    h1[4 * j4 + 2] = silu(a1.z); h1[4 * j4 + 3] = silu(a1.w);
  }

  // layer 2: h[64] -> radial[120], streamed in float4 output tiles
  const float4* w2v = (const float4*)s_w2;   // [64][30]
  const float4* b2v = (const float4*)s_b2;   // [30]
  for (int o4 = 0; o4 < 30; ++o4) {
    float4 a0 = b2v[o4], a1 = b2v[o4];
    #pragma unroll
    for (int j = 0; j < 64; ++j) {
      float4 w = w2v[j * 30 + o4];
      fma4(a0, h0[j], w);
      fma4(a1, h1[j], w);
    }
    a0 = silu4(a0); a1 = silu4(a1);
    if (e0v < E) radial4[(size_t)o4 * E + e0v] = a0;
    if (e1v < E) radial4[(size_t)o4 * E + e1v] = a1;
  }
}

// ---------------- Kernel 2: per-atom angular accumulation -> feat[216] ----------------
__global__ __launch_bounds__(256) void k_atom(
    const float* __restrict__ rij,
    const float4* __restrict__ radial4,
    const int* __restrict__ fai,
    float* __restrict__ feat, int E) {
  const int a = blockIdx.x;
  const int tid = threadIdx.x;
  __shared__ float s_rad[CE * 120];
  __shared__ float s_pw[CE * 15];
  __shared__ float s_gij[CE * KTOT];
  __shared__ float s_gi[NRADC * KTOT];
  __shared__ float s_feat[NFEAT];

  // binary search segment [start, end)
  int lo = 0, hi = E;
  while (lo < hi) { int mid = (lo + hi) >> 1; if (fai[mid] < a) lo = mid + 1; else hi = mid; }
  const int start = lo;
  hi = E;
  while (lo < hi) { int mid = (lo + hi) >> 1; if (fai[mid] < a + 1) lo = mid + 1; else hi = mid; }
  const int end = lo;

  // per-thread accumulator pairs: idx = tid + 256*p over 24*69=1656 cells
  float acc[7]; int roff[7]; int koff[7]; bool val[7];
  #pragma unroll
  for (int p = 0; p < 7; ++p) {
    int idx = tid + 256 * p;
    val[p] = (idx < NRADC * KTOT);
    int use = val[p] ? idx : 0;
    int rad = use / KTOT;
    int k = use - rad * KTOT;
    roff[p] = rad * 5 + 1 + c_zid[k];
    koff[p] = k;
    acc[p] = 0.0f;
  }
  float acc2b = 0.0f;  // 2-body, threads 0..23

  for (int c0 = start; c0 < end; c0 += CE) {
    const int ne = min(CE, end - c0);
    // stage radial (transposed global -> [e][120] LDS)
    for (int idx = tid; idx < 30 * ne; idx += 256) {
      int o4 = idx / ne;
      int e = idx - o4 * ne;
      float4 v = radial4[(size_t)o4 * E + (c0 + e)];
      float* dst = &s_rad[e * 120 + o4 * 4];
      dst[0] = v.x; dst[1] = v.y; dst[2] = v.z; dst[3] = v.w;
    }
    // unit-vector powers, one thread per edge
    if (tid < ne) {
      int eg = c0 + tid;
      float x = rij[eg * 3 + 0], y = rij[eg * 3 + 1], z = rij[eg * 3 + 2];
      float r = sqrtf(x * x + y * y + z * z);
      float inv = 1.0f / r;
      float p3[3] = {x * inv + 1e-12f, y * inv + 1e-12f, z * inv + 1e-12f};
      #pragma unroll
      for (int d = 0; d < 3; ++d) {
        float pw = 1.0f;
        #pragma unroll
        for (int n = 0; n < 5; ++n) { s_pw[tid * 15 + d * 5 + n] = pw; pw *= p3[d]; }
      }
    }
    __syncthreads();
    // g_ij for all (e,k)
    for (int idx = tid; idx < ne * KTOT; idx += 256) {
      int e = idx / KTOT;
      int k = idx - e * KTOT;
      s_gij[e * KTOT + k] = s_pw[e * 15 + c_lx[k]] * s_pw[e * 15 + 5 + c_ly[k]] *
                            s_pw[e * 15 + 10 + c_lz[k]] * c_fn[k];
    }
    __syncthreads();
    // accumulate
    for (int e = 0; e < ne; ++e) {
      const float* rr = &s_rad[e * 120];
      const float* gg = &s_gij[e * KTOT];
      #pragma unroll
      for (int p = 0; p < 7; ++p) acc[p] += rr[roff[p]] * gg[koff[p]];
      if (tid < NRADC) acc2b += rr[tid * 5];
    }
    __syncthreads();
  }

  #pragma unroll
  for (int p = 0; p < 7; ++p) if (val[p]) s_gi[tid + 256 * p] = acc[p];
  if (tid < NRADC) s_feat[tid] = acc2b;
  __syncthreads();

  if (tid < 192) {
    int zb = tid / NRADC;
    int rad = tid - zb * NRADC;
    int z = zb >> 1;
    bool neg = zb & 1;
    int k0 = c_k0[z], kn = c_kn[z];
    float s = 0.0f;
    for (int k = k0; k < k0 + kn; ++k) {
      float g = s_gi[rad * KTOT + k];
      float g2 = g * g;
      s += neg ? g2 * c_lam[k] : g2;
    }
    s_feat[NRADC + zb * NRADC + rad] = s * c_zn[z];
  }
  __syncthreads();
  if (tid < NFEAT) feat[(size_t)a * NFEAT + tid] = s_feat[tid];
}

// ---------------- species embedding (94 x 16) ----------------
__global__ void k_emb(const float* __restrict__ Ws1, const float* __restrict__ bs1,
                      const float* __restrict__ Ws2, const float* __restrict__ bs2,
                      float* __restrict__ emb) {
  int s = blockIdx.x, t = threadIdx.x;
  __shared__ float hh[32];
  if (t < 32) hh[t] = silu(Ws1[s * 32 + t] + bs1[t]);
  __syncthreads();
  if (t < EMBC) {
    float acc = bs2[t];
    #pragma unroll
    for (int c = 0; c < 32; ++c) acc += hh[c] * Ws2[c * EMBC + t];
    emb[s * EMBC + t] = acc;
  }
}

// ---------------- B[s,i,o] = sum_j emb[s,j] * Wa1[i*16+j, o] ----------------
__global__ __launch_bounds__(256) void k_B(const float* __restrict__ Wa1,
                                           const float* __restrict__ emb,
                                           float* __restrict__ B) {
  const int i = blockIdx.x;   // 0..215
  const int o = threadIdx.x;  // 0..255
  __shared__ float s_emb[NELEMC * EMBC];
  for (int idx = o; idx < NELEMC * EMBC; idx += 256) s_emb[idx] = emb[idx];
  float w[EMBC];
  #pragma unroll
  for (int j = 0; j < EMBC; ++j) w[j] = Wa1[(size_t)(i * EMBC + j) * H1C + o];
  __syncthreads();
  for (int s = 0; s < NELEMC; ++s) {
    float acc = 0.0f;
    #pragma unroll
    for (int j = 0; j < EMBC; ++j) acc += s_emb[s * EMBC + j] * w[j];
    B[((size_t)s * NFEAT + i) * H1C + o] = acc;
  }
}

// ---------------- counting sort of atoms by species ----------------
__global__ void k_sort(const int* __restrict__ sp, int* __restrict__ order, int nat) {
  __shared__ int cnt[NELEMC];
  __shared__ int off[NELEMC];
  int t = threadIdx.x;
  for (int i = t; i < NELEMC; i += 256) cnt[i] = 0;
  __syncthreads();
  for (int a = t; a < nat; a += 256) atomicAdd(&cnt[sp[a]], 1);
  __syncthreads();
  if (t == 0) { int run = 0; for (int s = 0; s < NELEMC; ++s) { off[s] = run; run += cnt[s]; } }
  __syncthreads();
  for (int a = t; a < nat; a += 256) { int pos = atomicAdd(&off[sp[a]], 1); order[pos] = a; }
}

// ---------------- per-atom MLP: feat@B[s] -> silu -> @Wa2 -> silu -> .Wa3 ----------------
__global__ __launch_bounds__(256) void k_mlp(
    const float* __restrict__ feat, const float* __restrict__ B,
    const float* __restrict__ ba1, const float* __restrict__ Wa2,
    const float* __restrict__ ba2, const float* __restrict__ Wa3,
    const float* __restrict__ ba3, const int* __restrict__ order,
    const int* __restrict__ sp, float* __restrict__ e_out, int nat) {
  const int nb = gridDim.x;
  int rank = blockIdx.x;
  if ((nb & 7) == 0) rank = (blockIdx.x & 7) * (nb >> 3) + (blockIdx.x >> 3);  // XCD swizzle
  const int a = order[rank];
  const int s = sp[a];
  const int t = threadIdx.x;
  __shared__ float s_feat[NFEAT];
  __shared__ float s_h1[H1C];
  __shared__ float s_red[H2C];
  if (t < NFEAT) s_feat[t] = feat[(size_t)a * NFEAT + t];
  __syncthreads();
  {
    double a0 = (double)ba1[t], a1 = 0.0;
    const float* Bp = B + (size_t)s * NFEAT * H1C + t;
    #pragma unroll 4
    for (int i = 0; i < NFEAT; i += 2) {
      a0 += (double)s_feat[i] * (double)Bp[(size_t)i * H1C];
      a1 += (double)s_feat[i + 1] * (double)Bp[(size_t)(i + 1) * H1C];
    }
    s_h1[t] = silu((float)(a0 + a1));
  }
  __syncthreads();
  if (t < H2C) {
    double a0 = (double)ba2[t], a1 = 0.0;
    #pragma unroll 4
    for (int j = 0; j < H1C; j += 2) {
      a0 += (double)s_h1[j] * (double)Wa2[j * H2C + t];
      a1 += (double)s_h1[j + 1] * (double)Wa2[(j + 1) * H2C + t];
    }
    float h2 = silu((float)(a0 + a1));
    s_red[t] = h2 * Wa3[t];
  }
  __syncthreads();
  if (t < 64) {
    float v = s_red[t] + s_red[t + 64];
    for (int o = 32; o; o >>= 1) v += __shfl_down(v, o, 64);
    if (t == 0) e_out[a] = v + ba3[0];
  }
}

// ---------------- final sum (double) ----------------
__global__ void k_reduce(const float* __restrict__ e_in, float* __restrict__ out, int nat) {
  int t = threadIdx.x;
  double acc = 0.0;
  for (int i = t; i < nat; i += 256) acc += (double)e_in[i];
  for (int o = 32; o; o >>= 1) acc += __shfl_down(acc, o, 64);
  __shared__ double s_par[4];
  if ((t & 63) == 0) s_par[t >> 6] = acc;
  __syncthreads();
  if (t == 0) out[0] = (float)(s_par[0] + s_par[1] + s_par[2] + s_par[3]);
}

extern "C" void kernel_launch(void* const* d_in, const int* in_sizes, int n_in,
                              void* d_out, int out_size, void* d_ws, size_t ws_size,
                              hipStream_t stream) {
  const float* rij = (const float*)d_in[0];
  const float* Wr1 = (const float*)d_in[1];
  const float* br1 = (const float*)d_in[2];
  const float* Wr2 = (const float*)d_in[3];
  const float* br2 = (const float*)d_in[4];
  const float* Ws1 = (const float*)d_in[5];
  const float* bs1 = (const float*)d_in[6];
  const float* Ws2 = (const float*)d_in[7];
  const float* bs2 = (const float*)d_in[8];
  const float* Wa1 = (const float*)d_in[9];
  const float* ba1 = (const float*)d_in[10];
  const float* Wa2 = (const float*)d_in[11];
  const float* ba2 = (const float*)d_in[12];
  const float* Wa3 = (const float*)d_in[13];
  const float* ba3 = (const float*)d_in[14];
  const int* fai = (const int*)d_in[15];
  const int* spc = (const int*)d_in[16];

  const int E = in_sizes[0] / 3;
  const int nat = in_sizes[16];

  float* ws = (float*)d_ws;
  size_t off = 0;
  float* radial = ws + off; off += (size_t)E * 120;          // transposed float4 [30][E]
  float* feat = ws + off;   off += (size_t)nat * NFEAT;
  float* emb = ws + off;    off += (size_t)NELEMC * EMBC;
  float* Bm = ws + off;     off += (size_t)NELEMC * NFEAT * H1C;
  float* e_ws = ws + off;   off += (size_t)nat;
  int* order = (int*)(ws + off);

  k_edge<<<(E + 255) / 256, 128, 0, stream>>>(rij, Wr1, br1, Wr2, br2, (float4*)radial, E);
  k_atom<<<nat, 256, 0, stream>>>(rij, (const float4*)radial, fai, feat, E);
  k_emb<<<NELEMC, 64, 0, stream>>>(Ws1, bs1, Ws2, bs2, emb);
  k_B<<<NFEAT, 256, 0, stream>>>(Wa1, emb, Bm);
  k_sort<<<1, 256, 0, stream>>>(spc, order, nat);
  k_mlp<<<nat, 256, 0, stream>>>(feat, Bm, ba1, Wa2, ba2, Wa3, ba3, order, spc, e_ws, nat);
  k_reduce<<<1, 256, 0, stream>>>(e_ws, (float*)d_out, nat);
}

// Round 2
// 232.169 us; speedup vs baseline: 1.9008x; 1.9008x over previous
//
#include <hip/hip_runtime.h>
#include <math.h>

#define KTOT 69
#define NRADC 24
#define NFEAT 216
#define NELEMC 94
#define EMBC 16
#define H1C 256
#define H2C 128
#define CE 8

// ---- static lxlylz tables (z=1..4 concatenated; offsets 0,4,14,34) ----
__device__ __constant__ int c_lx[KTOT] = {
  0,0,0,1,
  0,0,0,1,0,0,0,1,1,2,
  0,0,0,1,0,0,0,1,1,2,0,0,0,0,1,1,1,2,2,3,
  0,0,0,1,0,0,0,1,1,2,0,0,0,0,1,1,1,2,2,3,0,0,0,0,0,1,1,1,1,2,2,2,3,3,4};
__device__ __constant__ int c_ly[KTOT] = {
  0,0,1,0,
  0,0,1,0,0,1,2,0,1,0,
  0,0,1,0,0,1,2,0,1,0,0,1,2,3,0,1,2,0,1,0,
  0,0,1,0,0,1,2,0,1,0,0,1,2,3,0,1,2,0,1,0,0,1,2,3,4,0,1,2,3,0,1,2,0,1,0};
__device__ __constant__ int c_lz[KTOT] = {
  0,1,0,0,
  0,1,0,0,2,1,0,1,0,0,
  0,1,0,0,2,1,0,1,0,0,3,2,1,0,2,1,0,1,0,0,
  0,1,0,0,2,1,0,1,0,0,3,2,1,0,2,1,0,1,0,0,4,3,2,1,0,3,2,1,0,2,1,0,1,0,0};
__device__ __constant__ float c_fn[KTOT] = {
  1,1,1,1,
  1,2,2,2,1,2,1,2,2,1,
  1,3,3,3,3,6,3,6,6,3,1,3,3,1,3,6,3,3,3,1,
  1,4,4,4,6,12,6,12,12,6,4,12,12,4,12,24,12,12,12,4,
  1,4,6,4,1,4,12,12,4,6,12,6,4,4,1};
__device__ __constant__ float c_lam[KTOT] = {
  1,-1,-1,-1,
  1,-1,-1,-1,1,1,1,1,1,1,
  1,-1,-1,-1,1,1,1,1,1,1,-1,-1,-1,-1,-1,-1,-1,-1,-1,-1,
  1,-1,-1,-1,1,1,1,1,1,1,-1,-1,-1,-1,-1,-1,-1,-1,-1,-1,
  1,1,1,1,1,1,1,1,1,1,1,1,1,1,1};
__device__ __constant__ int c_zid[KTOT] = {
  0,0,0,0,
  1,1,1,1,1,1,1,1,1,1,
  2,2,2,2,2,2,2,2,2,2,2,2,2,2,2,2,2,2,2,2,
  3,3,3,3,3,3,3,3,3,3,3,3,3,3,3,3,3,3,3,3,3,3,3,3,3,3,3,3,3,3,3,3,3,3,3};
__device__ __constant__ int c_k0[4] = {0,4,14,34};
__device__ __constant__ int c_kn[4] = {4,10,20,35};
__device__ __constant__ float c_zn[4] = {1.0f, 0.5f, 0.25f, 0.125f};

__device__ __forceinline__ float silu(float x) { return x / (1.0f + expf(-x)); }
__device__ __forceinline__ float4 silu4(float4 v) {
  v.x = silu(v.x); v.y = silu(v.y); v.z = silu(v.z); v.w = silu(v.w); return v;
}
__device__ __forceinline__ void fma4(float4& a, float s, const float4 w) {
  a.x += s * w.x; a.y += s * w.y; a.z += s * w.z; a.w += s * w.w;
}

// ---------------- Kernel 1: per-edge radial MLP (v2: edge x ogroup parallel) ----
// Block: 256 threads = 64 edges x 4 output-groups. Grid = E/64 = 1024 blocks.
// Weights read wave-uniform from global (L1-resident); bas/h staged in LDS with
// conflict-free padding (stride 25 / 65 -> 2-way bank aliasing, free).
// radial output stored TRANSPOSED as float4: radial4[o4 * E + e], o4 in [0,30)
template <int NQ>
__device__ __forceinline__ void edge_layer2(
    const float* __restrict__ s_h, const float* __restrict__ Wr2,
    const float* __restrict__ br2, float4* __restrict__ radial4,
    int e, int og, int eg, int E) {
  float4 acc[NQ];
  const float4* b2 = (const float4*)(br2 + og * 32);
  #pragma unroll
  for (int q = 0; q < NQ; ++q) acc[q] = b2[q];
  #pragma unroll 2
  for (int j = 0; j < 64; ++j) {
    float hv = s_h[e * 65 + j];
    const float4* w = (const float4*)(Wr2 + j * 120 + og * 32);
    #pragma unroll
    for (int q = 0; q < NQ; ++q) fma4(acc[q], hv, w[q]);
  }
  if (eg < E) {
    #pragma unroll
    for (int q = 0; q < NQ; ++q)
      radial4[(size_t)(og * 8 + q) * E + eg] = silu4(acc[q]);
  }
}

__global__ __launch_bounds__(256) void k_edge(
    const float* __restrict__ rij,
    const float* __restrict__ Wr1, const float* __restrict__ br1,
    const float* __restrict__ Wr2, const float* __restrict__ br2,
    float4* __restrict__ radial4, int E) {
  __shared__ float s_bas[64 * 25];
  __shared__ float s_h[64 * 65];
  const int tid = threadIdx.x;
  const int e = tid & 63;
  const int og = __builtin_amdgcn_readfirstlane(tid >> 6);  // wave-uniform scalar
  const int eg = blockIdx.x * 64 + e;

  // basis: each thread computes 6 of the 24 gaussians for its edge
  {
    float x = 0.0f, y = 0.0f, z = 0.0f;
    if (eg < E) { x = rij[eg * 3 + 0]; y = rij[eg * 3 + 1]; z = rij[eg * 3 + 2]; }
    float r = sqrtf(x * x + y * y + z * z);
    float rc = fminf(r, 6.0f);
    float fcv = (eg < E)
        ? 0.5f * (cosf(3.14159265358979323846f * rc * (1.0f / 6.0f)) + 1.0f)
        : 0.0f;
    #pragma unroll
    for (int t = 0; t < 6; ++t) {
      int m = og * 6 + t;
      float d = r - (6.0f / 23.0f) * (float)m;
      s_bas[e * 25 + m] = expf(-8.0f * d * d) * fcv;
    }
  }
  __syncthreads();

  // layer 1: h[e][og*16 .. og*16+16), weights wave-uniform from global
  {
    const float4* b1 = (const float4*)(br1 + og * 16);
    float4 acc[4] = {b1[0], b1[1], b1[2], b1[3]};
    #pragma unroll 4
    for (int m = 0; m < NRADC; ++m) {
      float b = s_bas[e * 25 + m];
      const float4* w = (const float4*)(Wr1 + m * 64 + og * 16);
      #pragma unroll
      for (int q = 0; q < 4; ++q) fma4(acc[q], b, w[q]);
    }
    #pragma unroll
    for (int q = 0; q < 4; ++q) {
      float4 v = silu4(acc[q]);
      float* dst = &s_h[e * 65 + og * 16 + 4 * q];
      dst[0] = v.x; dst[1] = v.y; dst[2] = v.z; dst[3] = v.w;
    }
  }
  __syncthreads();

  // layer 2: out[e][og*32 .. og*32+32) (og==3: 24 outputs)
  if (og < 3) edge_layer2<8>(s_h, Wr2, br2, radial4, e, og, eg, E);
  else        edge_layer2<6>(s_h, Wr2, br2, radial4, e, og, eg, E);
}

// ---------------- Kernel 2: per-atom angular accumulation -> feat[216] ----------------
__global__ __launch_bounds__(256) void k_atom(
    const float* __restrict__ rij,
    const float4* __restrict__ radial4,
    const int* __restrict__ fai,
    float* __restrict__ feat, int E) {
  const int a = blockIdx.x;
  const int tid = threadIdx.x;
  __shared__ float s_rad[CE * 120];
  __shared__ float s_pw[CE * 15];
  __shared__ float s_gij[CE * KTOT];
  __shared__ float s_gi[NRADC * KTOT];
  __shared__ float s_feat[NFEAT];

  // binary search segment [start, end)
  int lo = 0, hi = E;
  while (lo < hi) { int mid = (lo + hi) >> 1; if (fai[mid] < a) lo = mid + 1; else hi = mid; }
  const int start = lo;
  hi = E;
  while (lo < hi) { int mid = (lo + hi) >> 1; if (fai[mid] < a + 1) lo = mid + 1; else hi = mid; }
  const int end = lo;

  // per-thread accumulator pairs: idx = tid + 256*p over 24*69=1656 cells
  float acc[7]; int roff[7]; int koff[7]; bool val[7];
  #pragma unroll
  for (int p = 0; p < 7; ++p) {
    int idx = tid + 256 * p;
    val[p] = (idx < NRADC * KTOT);
    int use = val[p] ? idx : 0;
    int rad = use / KTOT;
    int k = use - rad * KTOT;
    roff[p] = rad * 5 + 1 + c_zid[k];
    koff[p] = k;
    acc[p] = 0.0f;
  }
  float acc2b = 0.0f;  // 2-body, threads 0..23

  for (int c0 = start; c0 < end; c0 += CE) {
    const int ne = min(CE, end - c0);
    // stage radial (transposed global -> [e][120] LDS)
    for (int idx = tid; idx < 30 * ne; idx += 256) {
      int o4 = idx / ne;
      int e = idx - o4 * ne;
      float4 v = radial4[(size_t)o4 * E + (c0 + e)];
      float* dst = &s_rad[e * 120 + o4 * 4];
      dst[0] = v.x; dst[1] = v.y; dst[2] = v.z; dst[3] = v.w;
    }
    // unit-vector powers, one thread per edge
    if (tid < ne) {
      int eg = c0 + tid;
      float x = rij[eg * 3 + 0], y = rij[eg * 3 + 1], z = rij[eg * 3 + 2];
      float r = sqrtf(x * x + y * y + z * z);
      float inv = 1.0f / r;
      float p3[3] = {x * inv + 1e-12f, y * inv + 1e-12f, z * inv + 1e-12f};
      #pragma unroll
      for (int d = 0; d < 3; ++d) {
        float pw = 1.0f;
        #pragma unroll
        for (int n = 0; n < 5; ++n) { s_pw[tid * 15 + d * 5 + n] = pw; pw *= p3[d]; }
      }
    }
    __syncthreads();
    // g_ij for all (e,k)
    for (int idx = tid; idx < ne * KTOT; idx += 256) {
      int e = idx / KTOT;
      int k = idx - e * KTOT;
      s_gij[e * KTOT + k] = s_pw[e * 15 + c_lx[k]] * s_pw[e * 15 + 5 + c_ly[k]] *
                            s_pw[e * 15 + 10 + c_lz[k]] * c_fn[k];
    }
    __syncthreads();
    // accumulate
    for (int e = 0; e < ne; ++e) {
      const float* rr = &s_rad[e * 120];
      const float* gg = &s_gij[e * KTOT];
      #pragma unroll
      for (int p = 0; p < 7; ++p) acc[p] += rr[roff[p]] * gg[koff[p]];
      if (tid < NRADC) acc2b += rr[tid * 5];
    }
    __syncthreads();
  }

  #pragma unroll
  for (int p = 0; p < 7; ++p) if (val[p]) s_gi[tid + 256 * p] = acc[p];
  if (tid < NRADC) s_feat[tid] = acc2b;
  __syncthreads();

  if (tid < 192) {
    int zb = tid / NRADC;
    int rad = tid - zb * NRADC;
    int z = zb >> 1;
    bool neg = zb & 1;
    int k0 = c_k0[z], kn = c_kn[z];
    float s = 0.0f;
    for (int k = k0; k < k0 + kn; ++k) {
      float g = s_gi[rad * KTOT + k];
      float g2 = g * g;
      s += neg ? g2 * c_lam[k] : g2;
    }
    s_feat[NRADC + zb * NRADC + rad] = s * c_zn[z];
  }
  __syncthreads();
  if (tid < NFEAT) feat[(size_t)a * NFEAT + tid] = s_feat[tid];
}

// ---------------- species embedding (94 x 16) ----------------
__global__ void k_emb(const float* __restrict__ Ws1, const float* __restrict__ bs1,
                      const float* __restrict__ Ws2, const float* __restrict__ bs2,
                      float* __restrict__ emb) {
  int s = blockIdx.x, t = threadIdx.x;
  __shared__ float hh[32];
  if (t < 32) hh[t] = silu(Ws1[s * 32 + t] + bs1[t]);
  __syncthreads();
  if (t < EMBC) {
    float acc = bs2[t];
    #pragma unroll
    for (int c = 0; c < 32; ++c) acc += hh[c] * Ws2[c * EMBC + t];
    emb[s * EMBC + t] = acc;
  }
}

// ---------------- B[s,i,o] = sum_j emb[s,j] * Wa1[i*16+j, o] ----------------
__global__ __launch_bounds__(256) void k_B(const float* __restrict__ Wa1,
                                           const float* __restrict__ emb,
                                           float* __restrict__ B) {
  const int i = blockIdx.x;   // 0..215
  const int o = threadIdx.x;  // 0..255
  __shared__ float s_emb[NELEMC * EMBC];
  for (int idx = o; idx < NELEMC * EMBC; idx += 256) s_emb[idx] = emb[idx];
  float w[EMBC];
  #pragma unroll
  for (int j = 0; j < EMBC; ++j) w[j] = Wa1[(size_t)(i * EMBC + j) * H1C + o];
  __syncthreads();
  for (int s = 0; s < NELEMC; ++s) {
    float acc = 0.0f;
    #pragma unroll
    for (int j = 0; j < EMBC; ++j) acc += s_emb[s * EMBC + j] * w[j];
    B[((size_t)s * NFEAT + i) * H1C + o] = acc;
  }
}

// ---------------- counting sort of atoms by species ----------------
__global__ void k_sort(const int* __restrict__ sp, int* __restrict__ order, int nat) {
  __shared__ int cnt[NELEMC];
  __shared__ int off[NELEMC];
  int t = threadIdx.x;
  for (int i = t; i < NELEMC; i += 256) cnt[i] = 0;
  __syncthreads();
  for (int a = t; a < nat; a += 256) atomicAdd(&cnt[sp[a]], 1);
  __syncthreads();
  if (t == 0) { int run = 0; for (int s = 0; s < NELEMC; ++s) { off[s] = run; run += cnt[s]; } }
  __syncthreads();
  for (int a = t; a < nat; a += 256) { int pos = atomicAdd(&off[sp[a]], 1); order[pos] = a; }
}

// ---------------- per-atom MLP: feat@B[s] -> silu -> @Wa2 -> silu -> .Wa3 ----------------
__global__ __launch_bounds__(256) void k_mlp(
    const float* __restrict__ feat, const float* __restrict__ B,
    const float* __restrict__ ba1, const float* __restrict__ Wa2,
    const float* __restrict__ ba2, const float* __restrict__ Wa3,
    const float* __restrict__ ba3, const int* __restrict__ order,
    const int* __restrict__ sp, float* __restrict__ e_out, int nat) {
  const int nb = gridDim.x;
  int rank = blockIdx.x;
  if ((nb & 7) == 0) rank = (blockIdx.x & 7) * (nb >> 3) + (blockIdx.x >> 3);  // XCD swizzle
  const int a = order[rank];
  const int s = sp[a];
  const int t = threadIdx.x;
  __shared__ float s_feat[NFEAT];
  __shared__ float s_h1[H1C];
  __shared__ float s_red[H2C];
  if (t < NFEAT) s_feat[t] = feat[(size_t)a * NFEAT + t];
  __syncthreads();
  {
    double a0 = (double)ba1[t], a1 = 0.0;
    const float* Bp = B + (size_t)s * NFEAT * H1C + t;
    #pragma unroll 4
    for (int i = 0; i < NFEAT; i += 2) {
      a0 += (double)s_feat[i] * (double)Bp[(size_t)i * H1C];
      a1 += (double)s_feat[i + 1] * (double)Bp[(size_t)(i + 1) * H1C];
    }
    s_h1[t] = silu((float)(a0 + a1));
  }
  __syncthreads();
  if (t < H2C) {
    double a0 = (double)ba2[t], a1 = 0.0;
    #pragma unroll 4
    for (int j = 0; j < H1C; j += 2) {
      a0 += (double)s_h1[j] * (double)Wa2[j * H2C + t];
      a1 += (double)s_h1[j + 1] * (double)Wa2[(j + 1) * H2C + t];
    }
    float h2 = silu((float)(a0 + a1));
    s_red[t] = h2 * Wa3[t];
  }
  __syncthreads();
  if (t < 64) {
    float v = s_red[t] + s_red[t + 64];
    for (int o = 32; o; o >>= 1) v += __shfl_down(v, o, 64);
    if (t == 0) e_out[a] = v + ba3[0];
  }
}

// ---------------- final sum (double) ----------------
__global__ void k_reduce(const float* __restrict__ e_in, float* __restrict__ out, int nat) {
  int t = threadIdx.x;
  double acc = 0.0;
  for (int i = t; i < nat; i += 256) acc += (double)e_in[i];
  for (int o = 32; o; o >>= 1) acc += __shfl_down(acc, o, 64);
  __shared__ double s_par[4];
  if ((t & 63) == 0) s_par[t >> 6] = acc;
  __syncthreads();
  if (t == 0) out[0] = (float)(s_par[0] + s_par[1] + s_par[2] + s_par[3]);
}

extern "C" void kernel_launch(void* const* d_in, const int* in_sizes, int n_in,
                              void* d_out, int out_size, void* d_ws, size_t ws_size,
                              hipStream_t stream) {
  const float* rij = (const float*)d_in[0];
  const float* Wr1 = (const float*)d_in[1];
  const float* br1 = (const float*)d_in[2];
  const float* Wr2 = (const float*)d_in[3];
  const float* br2 = (const float*)d_in[4];
  const float* Ws1 = (const float*)d_in[5];
  const float* bs1 = (const float*)d_in[6];
  const float* Ws2 = (const float*)d_in[7];
  const float* bs2 = (const float*)d_in[8];
  const float* Wa1 = (const float*)d_in[9];
  const float* ba1 = (const float*)d_in[10];
  const float* Wa2 = (const float*)d_in[11];
  const float* ba2 = (const float*)d_in[12];
  const float* Wa3 = (const float*)d_in[13];
  const float* ba3 = (const float*)d_in[14];
  const int* fai = (const int*)d_in[15];
  const int* spc = (const int*)d_in[16];

  const int E = in_sizes[0] / 3;
  const int nat = in_sizes[16];

  float* ws = (float*)d_ws;
  size_t off = 0;
  float* radial = ws + off; off += (size_t)E * 120;          // transposed float4 [30][E]
  float* feat = ws + off;   off += (size_t)nat * NFEAT;
  float* emb = ws + off;    off += (size_t)NELEMC * EMBC;
  float* Bm = ws + off;     off += (size_t)NELEMC * NFEAT * H1C;
  float* e_ws = ws + off;   off += (size_t)nat;
  int* order = (int*)(ws + off);

  k_edge<<<(E + 63) / 64, 256, 0, stream>>>(rij, Wr1, br1, Wr2, br2, (float4*)radial, E);
  k_atom<<<nat, 256, 0, stream>>>(rij, (const float4*)radial, fai, feat, E);
  k_emb<<<NELEMC, 64, 0, stream>>>(Ws1, bs1, Ws2, bs2, emb);
  k_B<<<NFEAT, 256, 0, stream>>>(Wa1, emb, Bm);
  k_sort<<<1, 256, 0, stream>>>(spc, order, nat);
  k_mlp<<<nat, 256, 0, stream>>>(feat, Bm, ba1, Wa2, ba2, Wa3, ba3, order, spc, e_ws, nat);
  k_reduce<<<1, 256, 0, stream>>>(e_ws, (float*)d_out, nat);
}